// Round 1
// baseline (332.819 us; speedup 1.0000x reference)
//
#include <hip/hip_runtime.h>

using u16 = unsigned short;
using u32 = unsigned int;

#define B_   2
#define N_   2048
#define DIM_ 1024
#define H_   16
#define D_   64
#define ROWS_ (B_*N_)   // 4096
#define E3_  3072       // q|k|v concatenated

typedef __attribute__((ext_vector_type(8))) short short8;
typedef __attribute__((ext_vector_type(4))) float f32x4;

__device__ __forceinline__ u16 f2bf(float f) {
  u32 u = __builtin_bit_cast(u32, f);
  u32 r = (u + 0x7FFFu + ((u >> 16) & 1u)) >> 16;
  return (u16)r;
}
__device__ __forceinline__ float bf2f(u16 h) {
  u32 u = ((u32)h) << 16;
  return __builtin_bit_cast(float, u);
}
__device__ __forceinline__ short8 ld8(const u16* p) { return *(const short8*)p; }
__device__ __forceinline__ f32x4 mfma16(short8 a, short8 b, f32x4 c) {
  return __builtin_amdgcn_mfma_f32_16x16x32_bf16(a, b, c, 0, 0, 0);
}
__device__ __forceinline__ void lds16(const u16* g, u16* l) {
  __builtin_amdgcn_global_load_lds(
      (const __attribute__((address_space(1))) void*)g,
      (__attribute__((address_space(3))) void*)l, 16, 0, 0);
}

// ---------------- LayerNorm: x fp32 [4096][1024] -> xn bf16 ----------------
__global__ __launch_bounds__(256) void k_layernorm(const float* __restrict__ x,
                                                   const float* __restrict__ gamma,
                                                   u16* __restrict__ xn) {
  int row = blockIdx.x, tid = threadIdx.x;
  const float4 xv = *(const float4*)(x + (size_t)row * DIM_ + tid * 4);
  float s = xv.x + xv.y + xv.z + xv.w;
  float q = xv.x*xv.x + xv.y*xv.y + xv.z*xv.z + xv.w*xv.w;
  for (int off = 32; off; off >>= 1) { s += __shfl_xor(s, off); q += __shfl_xor(q, off); }
  __shared__ float red[8];
  int wave = tid >> 6, lane = tid & 63;
  if (lane == 0) { red[wave] = s; red[4 + wave] = q; }
  __syncthreads();
  s = red[0] + red[1] + red[2] + red[3];
  q = red[4] + red[5] + red[6] + red[7];
  float mu  = s * (1.0f / DIM_);
  float var = q * (1.0f / DIM_) - mu * mu;
  float inv = rsqrtf(var + 1e-5f);
  const float4 gv = *(const float4*)(gamma + tid * 4);
  ushort4 ov;
  ov.x = f2bf((xv.x - mu) * inv * gv.x);
  ov.y = f2bf((xv.y - mu) * inv * gv.y);
  ov.z = f2bf((xv.z - mu) * inv * gv.z);
  ov.w = f2bf((xv.w - mu) * inv * gv.w);
  *(ushort4*)(xn + (size_t)row * DIM_ + tid * 4) = ov;
}

// ------------- transpose+cast: in fp32 [1024][ncols] -> out bf16 [ncols][1024]
__global__ __launch_bounds__(256) void k_tcast(const float* __restrict__ in,
                                               u16* __restrict__ out, int ncols) {
  __shared__ float tile[32][33];
  int tx = threadIdx.x, ty = threadIdx.y;
  int col  = blockIdx.x * 32 + tx;   // ncols dim
  int row0 = blockIdx.y * 32;        // K dim
  for (int j = 0; j < 32; j += 8)
    tile[ty + j][tx] = in[(size_t)(row0 + ty + j) * ncols + col];
  __syncthreads();
  int orow = blockIdx.x * 32 + ty;
  int ocol = row0 + tx;
  for (int j = 0; j < 32; j += 8)
    out[(size_t)(orow + j) * DIM_ + ocol] = f2bf(tile[tx][ty + j]);
}

// ------------- mask decode with dtype auto-detect -> additive bias ---------
__global__ void k_mask(const int* __restrict__ mraw, float* __restrict__ bias) {
  __shared__ int flag;
  int tid = threadIdx.x;
  if (tid == 0) flag = 0;
  __syncthreads();
  int v = mraw[tid];                 // 1024 ints: safe under bool(4096B) or int32(16384B)
  if (v != 0 && v != 1) atomicOr(&flag, 1);
  __syncthreads();
  bool bytemode = (flag != 0);
  const unsigned char* mb = (const unsigned char*)mraw;
  for (int j = tid; j < B_ * N_; j += 1024) {
    bool valid = bytemode ? (mb[j] != 0) : (mraw[j] != 0);
    bias[j] = valid ? 0.0f : -1e30f;
  }
}

// ------------- GEMM C = A @ Bt^T : A[M][K] bf16, Bt[N][K] bf16 -------------
template <bool OUT_BF16>
__global__ __launch_bounds__(256) void k_gemm_bt(const u16* __restrict__ A,
                                                 const u16* __restrict__ Bt,
                                                 void* __restrict__ Cv,
                                                 int M, int Ncols, int K) {
  __shared__ u16 As[128 * 32];
  __shared__ u16 Bs[128 * 32];
  const int tid = threadIdx.x;
  const int wave = tid >> 6, lane = tid & 63;
  const int g = lane >> 4, li = lane & 15;
  const int tm = blockIdx.x * 128, tn = blockIdx.y * 128;
  const int wm = (wave >> 1) * 64, wn = (wave & 1) * 64;
  const int srow = wave * 16 + (lane >> 2);
  const int scol = (lane & 3) * 8;

  f32x4 acc[4][4];
#pragma unroll
  for (int i = 0; i < 4; ++i)
#pragma unroll
    for (int j = 0; j < 4; ++j) acc[i][j] = (f32x4){0.f, 0.f, 0.f, 0.f};

  const u16* ag = A  + (size_t)(tm + srow) * K + scol;
  const u16* bg = Bt + (size_t)(tn + srow) * K + scol;

  for (int k0 = 0; k0 < K; k0 += 32) {
    __syncthreads();                           // previous reads done
#pragma unroll
    for (int p = 0; p < 2; ++p) {
      lds16(ag + (size_t)p * 64 * K + k0, As + p * 2048 + wave * 512);
      lds16(bg + (size_t)p * 64 * K + k0, Bs + p * 2048 + wave * 512);
    }
    __syncthreads();                           // drains vmcnt, staging visible
    short8 af[4], bfm[4];
#pragma unroll
    for (int m = 0; m < 4; ++m) af[m]  = ld8(As + (wm + m * 16 + li) * 32 + g * 8);
#pragma unroll
    for (int n = 0; n < 4; ++n) bfm[n] = ld8(Bs + (wn + n * 16 + li) * 32 + g * 8);
#pragma unroll
    for (int m = 0; m < 4; ++m)
#pragma unroll
      for (int n = 0; n < 4; ++n)
        acc[m][n] = mfma16(af[m], bfm[n], acc[m][n]);
  }
#pragma unroll
  for (int m = 0; m < 4; ++m)
#pragma unroll
    for (int n = 0; n < 4; ++n) {
      int row = tm + wm + m * 16 + g * 4;
      int col = tn + wn + n * 16 + li;
#pragma unroll
      for (int r = 0; r < 4; ++r) {
        float v = acc[m][n][r];
        if (OUT_BF16) ((u16*)Cv)[(size_t)(row + r) * Ncols + col] = f2bf(v);
        else          ((float*)Cv)[(size_t)(row + r) * Ncols + col] = v;
      }
    }
}

// ------------- RMS qk-norm: Cq bf16 [4096][3072] -> q,k bf16 [b,h,n,d] -----
__global__ __launch_bounds__(256) void k_rms_qk(const u16* __restrict__ Cq,
                                                const float* __restrict__ gq,
                                                const float* __restrict__ gk,
                                                u16* __restrict__ qo,
                                                u16* __restrict__ ko) {
  int gid  = blockIdx.x * 4 + (threadIdx.x >> 6);   // 0..131071
  int lane = threadIdx.x & 63;
  int hh  = gid & 31;           // 0-15: q heads, 16-31: k heads
  int row = gid >> 5;           // 0..4095
  int b = row >> 11, n = row & 2047;
  bool isq = hh < 16;
  int h = hh & 15;
  int col = (isq ? 0 : 1024) + h * 64 + lane;
  float v = bf2f(Cq[(size_t)row * E3_ + col]);
  float ss = v * v;
  for (int off = 32; off; off >>= 1) ss += __shfl_xor(ss, off);
  float nrm = sqrtf(ss);
  float scale = 8.0f / fmaxf(nrm, 1e-12f);   // sqrt(64)=8
  const float* gam = isq ? gq : gk;
  float outv = v * scale * gam[h * 64 + lane];
  u16* dst = isq ? qo : ko;
  dst[(((size_t)(b * H_ + h)) * N_ + n) * 64 + lane] = f2bf(outv);
}

// ------------- V relayout: Cq[.,2048+h*64+d] -> vT [b*h][d][n] -------------
__global__ __launch_bounds__(256) void k_vt(const u16* __restrict__ Cq,
                                            u16* __restrict__ vT) {
  __shared__ float tile[64][65];
  int bh = blockIdx.y;
  int b = bh >> 4, h = bh & 15;
  int n0 = blockIdx.x * 64;
  int tx = threadIdx.x, ty = threadIdx.y;
  for (int i = 0; i < 64; i += 4) {
    int n = n0 + ty + i;
    tile[ty + i][tx] = bf2f(Cq[((size_t)(b * N_ + n)) * E3_ + 2048 + h * 64 + tx]);
  }
  __syncthreads();
  u16* dst = vT + (size_t)bh * 64 * N_;
  for (int i = 0; i < 64; i += 4) {
    int d = ty + i;
    dst[(size_t)d * N_ + n0 + tx] = f2bf(tile[tx][d]);
  }
}

// ------------- flash attention: per (b,h), 64 q-rows per block -------------
__global__ __launch_bounds__(256) void k_attn(const u16* __restrict__ Q,
                                              const u16* __restrict__ K,
                                              const u16* __restrict__ Vt,
                                              const float* __restrict__ bias,
                                              u16* __restrict__ Out) {
  __shared__ float bias_s[N_];          // 8 KB
  __shared__ u16 p_lds[4][16 * 80];     // per-wave P tile, padded stride 80
  int bh = blockIdx.y;
  int b = bh >> 4, h = bh & 15;
  int qb = blockIdx.x * 64;
  int tid = threadIdx.x, wave = tid >> 6, lane = tid & 63;
  int g = lane >> 4, li = lane & 15;
  const u16* Qh = Q  + (size_t)bh * N_ * 64;
  const u16* Kh = K  + (size_t)bh * N_ * 64;
  const u16* Vh = Vt + (size_t)bh * 64 * N_;

  for (int j = tid; j < N_; j += 256) bias_s[j] = bias[b * N_ + j];
  __syncthreads();

  int qr = qb + wave * 16 + li;
  short8 aq0 = ld8(Qh + (size_t)qr * 64 + g * 8);
  short8 aq1 = ld8(Qh + (size_t)qr * 64 + 32 + g * 8);

  f32x4 oacc[4];
#pragma unroll
  for (int dc = 0; dc < 4; ++dc) oacc[dc] = (f32x4){0.f, 0.f, 0.f, 0.f};
  float m[4] = {-3e38f, -3e38f, -3e38f, -3e38f};
  float l[4] = {0.f, 0.f, 0.f, 0.f};
  u16* pl = &p_lds[wave][0];

  for (int kt = 0; kt < N_ / 64; ++kt) {
    int kbase = kt * 64;
    f32x4 s[4];
#pragma unroll
    for (int c = 0; c < 4; ++c) {
      const u16* kp = Kh + (size_t)(kbase + c * 16 + li) * 64 + g * 8;
      short8 bk0 = ld8(kp);
      short8 bk1 = ld8(kp + 32);
      f32x4 z = (f32x4){0.f, 0.f, 0.f, 0.f};
      z = mfma16(aq0, bk0, z);
      s[c] = mfma16(aq1, bk1, z);
    }
    float sv[4][4], rowmax[4];
#pragma unroll
    for (int r = 0; r < 4; ++r) rowmax[r] = -3e38f;
#pragma unroll
    for (int c = 0; c < 4; ++c) {
      float bb = bias_s[kbase + c * 16 + li];
#pragma unroll
      for (int r = 0; r < 4; ++r) {
        float t = s[c][r] + bb;
        sv[c][r] = t;
        rowmax[r] = fmaxf(rowmax[r], t);
      }
    }
#pragma unroll
    for (int off = 1; off < 16; off <<= 1)
#pragma unroll
      for (int r = 0; r < 4; ++r)
        rowmax[r] = fmaxf(rowmax[r], __shfl_xor(rowmax[r], off));
    float sc[4], rsum[4];
#pragma unroll
    for (int r = 0; r < 4; ++r) {
      float mn = fmaxf(m[r], rowmax[r]);
      sc[r] = __expf(m[r] - mn);
      m[r] = mn;
      rsum[r] = 0.f;
    }
#pragma unroll
    for (int c = 0; c < 4; ++c)
#pragma unroll
      for (int r = 0; r < 4; ++r) {
        float p = __expf(sv[c][r] - m[r]);
        rsum[r] += p;
        pl[(g * 4 + r) * 80 + c * 16 + li] = f2bf(p);
      }
#pragma unroll
    for (int off = 1; off < 16; off <<= 1)
#pragma unroll
      for (int r = 0; r < 4; ++r) rsum[r] += __shfl_xor(rsum[r], off);
#pragma unroll
    for (int r = 0; r < 4; ++r) l[r] = l[r] * sc[r] + rsum[r];
#pragma unroll
    for (int dc = 0; dc < 4; ++dc)
#pragma unroll
      for (int r = 0; r < 4; ++r) oacc[dc][r] *= sc[r];
    // PV: read P back in A-layout, V from vT in B-layout (contiguous 16B)
    short8 ap0 = ld8(pl + li * 80 + g * 8);
    short8 ap1 = ld8(pl + li * 80 + 32 + g * 8);
#pragma unroll
    for (int dc = 0; dc < 4; ++dc) {
      const u16* vp = Vh + (size_t)(dc * 16 + li) * N_ + kbase + g * 8;
      short8 bv0 = ld8(vp);
      short8 bv1 = ld8(vp + 32);
      oacc[dc] = mfma16(ap0, bv0, oacc[dc]);
      oacc[dc] = mfma16(ap1, bv1, oacc[dc]);
    }
  }
#pragma unroll
  for (int dc = 0; dc < 4; ++dc)
#pragma unroll
    for (int r = 0; r < 4; ++r) {
      int row = qb + wave * 16 + g * 4 + r;
      int col = h * 64 + dc * 16 + li;
      Out[((size_t)(b * N_ + row)) * DIM_ + col] = f2bf(oacc[dc][r] / l[r]);
    }
}

// ---------------------------------------------------------------------------
extern "C" void kernel_launch(void* const* d_in, const int* in_sizes, int n_in,
                              void* d_out, int out_size, void* d_ws, size_t ws_size,
                              hipStream_t stream) {
  const float* x    = (const float*)d_in[0];
  const int*   mask = (const int*)d_in[1];
  const float* g_ln = (const float*)d_in[2];
  const float* g_q  = (const float*)d_in[3];
  const float* g_k  = (const float*)d_in[4];
  const float* Wq   = (const float*)d_in[5];
  const float* Wkv  = (const float*)d_in[6];
  const float* Wo   = (const float*)d_in[7];
  float* out = (float*)d_out;

  char* ws = (char*)d_ws;
  u16*   xn   = (u16*)(ws);                         // 8 MB
  u16*   Wt   = (u16*)(ws + 8388608);               // 6 MB  (Wq^T | Wkv^T) [3072][1024]
  u16*   Wot  = (u16*)(ws + 14680064);              // 2 MB  Wo^T [1024][1024]
  float* bias = (float*)(ws + 16777216);            // 16 KB
  u16*   Cq   = (u16*)(ws + 16793600);              // 24 MB [4096][3072]
  u16*   qb   = (u16*)(ws + 41959424);              // 8 MB [b,h,n,d]
  u16*   kb   = (u16*)(ws + 41959424 + 8388608);    // 8 MB
  u16*   vT   = (u16*)(ws + 41959424 + 2*8388608);  // 8 MB [b*h][d][n]
  u16*   ao   = (u16*)(ws + 41959424 + 3*8388608);  // 8 MB [4096][1024]

  k_layernorm<<<ROWS_, 256, 0, stream>>>(x, g_ln, xn);
  dim3 tcb(32, 8);
  k_tcast<<<dim3(32, 32), tcb, 0, stream>>>(Wq,  Wt,               1024);
  k_tcast<<<dim3(64, 32), tcb, 0, stream>>>(Wkv, Wt + 1024 * 1024, 2048);
  k_tcast<<<dim3(32, 32), tcb, 0, stream>>>(Wo,  Wot,              1024);
  k_mask<<<1, 1024, 0, stream>>>(mask, bias);
  k_gemm_bt<true><<<dim3(32, 24), 256, 0, stream>>>(xn, Wt, Cq, ROWS_, E3_, DIM_);
  k_rms_qk<<<32768, 256, 0, stream>>>(Cq, g_q, g_k, qb, kb);
  k_vt<<<dim3(32, 32), dim3(64, 4), 0, stream>>>(Cq, vT);
  k_attn<<<dim3(32, 32), 256, 0, stream>>>(qb, kb, vT, bias, ao);
  k_gemm_bt<false><<<dim3(32, 8), 256, 0, stream>>>(ao, Wot, out, ROWS_, DIM_, DIM_);
}

// Round 2
// 332.279 us; speedup vs baseline: 1.0016x; 1.0016x over previous
//
#include <hip/hip_runtime.h>

using u16 = unsigned short;
using u32 = unsigned int;

#define B_   2
#define N_   2048
#define DIM_ 1024
#define H_   16
#define D_   64
#define ROWS_ (B_*N_)   // 4096
#define E3_  3072       // q|k|v concatenated

typedef __attribute__((ext_vector_type(8))) short short8;
typedef __attribute__((ext_vector_type(4))) float f32x4;

__device__ __forceinline__ u16 f2bf(float f) {
  u32 u = __builtin_bit_cast(u32, f);
  u32 r = (u + 0x7FFFu + ((u >> 16) & 1u)) >> 16;
  return (u16)r;
}
__device__ __forceinline__ float bf2f(u16 h) {
  u32 u = ((u32)h) << 16;
  return __builtin_bit_cast(float, u);
}
__device__ __forceinline__ short8 ld8(const u16* p) { return *(const short8*)p; }
__device__ __forceinline__ f32x4 mfma16(short8 a, short8 b, f32x4 c) {
  return __builtin_amdgcn_mfma_f32_16x16x32_bf16(a, b, c, 0, 0, 0);
}
__device__ __forceinline__ void lds16(const u16* g, u16* l) {
  __builtin_amdgcn_global_load_lds(
      (const __attribute__((address_space(1))) void*)g,
      (__attribute__((address_space(3))) void*)l, 16, 0, 0);
}

// ---------------- LayerNorm: x fp32 [4096][1024] -> xn bf16 ----------------
__global__ __launch_bounds__(256) void k_layernorm(const float* __restrict__ x,
                                                   const float* __restrict__ gamma,
                                                   u16* __restrict__ xn) {
  int row = blockIdx.x, tid = threadIdx.x;
  const float4 xv = *(const float4*)(x + (size_t)row * DIM_ + tid * 4);
  float s = xv.x + xv.y + xv.z + xv.w;
  float q = xv.x*xv.x + xv.y*xv.y + xv.z*xv.z + xv.w*xv.w;
  for (int off = 32; off; off >>= 1) { s += __shfl_xor(s, off); q += __shfl_xor(q, off); }
  __shared__ float red[8];
  int wave = tid >> 6, lane = tid & 63;
  if (lane == 0) { red[wave] = s; red[4 + wave] = q; }
  __syncthreads();
  s = red[0] + red[1] + red[2] + red[3];
  q = red[4] + red[5] + red[6] + red[7];
  float mu  = s * (1.0f / DIM_);
  float var = q * (1.0f / DIM_) - mu * mu;
  float inv = rsqrtf(var + 1e-5f);
  const float4 gv = *(const float4*)(gamma + tid * 4);
  ushort4 ov;
  ov.x = f2bf((xv.x - mu) * inv * gv.x);
  ov.y = f2bf((xv.y - mu) * inv * gv.y);
  ov.z = f2bf((xv.z - mu) * inv * gv.z);
  ov.w = f2bf((xv.w - mu) * inv * gv.w);
  *(ushort4*)(xn + (size_t)row * DIM_ + tid * 4) = ov;
}

// ------------- transpose+cast: in fp32 [1024][ncols] -> out bf16 [ncols][1024]
__global__ __launch_bounds__(256) void k_tcast(const float* __restrict__ in,
                                               u16* __restrict__ out, int ncols) {
  __shared__ float tile[32][33];
  int tx = threadIdx.x, ty = threadIdx.y;
  int col  = blockIdx.x * 32 + tx;   // ncols dim
  int row0 = blockIdx.y * 32;        // K dim
  for (int j = 0; j < 32; j += 8)
    tile[ty + j][tx] = in[(size_t)(row0 + ty + j) * ncols + col];
  __syncthreads();
  int orow = blockIdx.x * 32 + ty;
  int ocol = row0 + tx;
  for (int j = 0; j < 32; j += 8)
    out[(size_t)(orow + j) * DIM_ + ocol] = f2bf(tile[tx][ty + j]);
}

// ------------- mask decode with dtype auto-detect -> additive bias ---------
__global__ void k_mask(const int* __restrict__ mraw, float* __restrict__ bias) {
  __shared__ int flag;
  int tid = threadIdx.x;
  if (tid == 0) flag = 0;
  __syncthreads();
  int v = mraw[tid];                 // 1024 ints: safe under bool(4096B) or int32(16384B)
  if (v != 0 && v != 1) atomicOr(&flag, 1);
  __syncthreads();
  bool bytemode = (flag != 0);
  const unsigned char* mb = (const unsigned char*)mraw;
  for (int j = tid; j < B_ * N_; j += 1024) {
    bool valid = bytemode ? (mb[j] != 0) : (mraw[j] != 0);
    bias[j] = valid ? 0.0f : -1e30f;
  }
}

// ------------- GEMM C = A @ Bt^T : A[M][K] bf16, Bt[N][K] bf16 -------------
template <bool OUT_BF16>
__global__ __launch_bounds__(256) void k_gemm_bt(const u16* __restrict__ A,
                                                 const u16* __restrict__ Bt,
                                                 void* __restrict__ Cv,
                                                 int M, int Ncols, int K) {
  __shared__ u16 As[128 * 32];
  __shared__ u16 Bs[128 * 32];
  const int tid = threadIdx.x;
  const int wave = tid >> 6, lane = tid & 63;
  const int g = lane >> 4, li = lane & 15;
  const int tm = blockIdx.x * 128, tn = blockIdx.y * 128;
  const int wm = (wave >> 1) * 64, wn = (wave & 1) * 64;
  const int srow = wave * 16 + (lane >> 2);
  const int scol = (lane & 3) * 8;

  f32x4 acc[4][4];
#pragma unroll
  for (int i = 0; i < 4; ++i)
#pragma unroll
    for (int j = 0; j < 4; ++j) acc[i][j] = (f32x4){0.f, 0.f, 0.f, 0.f};

  const u16* ag = A  + (size_t)(tm + srow) * K + scol;
  const u16* bg = Bt + (size_t)(tn + srow) * K + scol;

  for (int k0 = 0; k0 < K; k0 += 32) {
    __syncthreads();                           // previous reads done
#pragma unroll
    for (int p = 0; p < 2; ++p) {
      lds16(ag + (size_t)p * 64 * K + k0, As + p * 2048 + wave * 512);
      lds16(bg + (size_t)p * 64 * K + k0, Bs + p * 2048 + wave * 512);
    }
    __syncthreads();                           // drains vmcnt, staging visible
    short8 af[4], bfm[4];
#pragma unroll
    for (int m = 0; m < 4; ++m) af[m]  = ld8(As + (wm + m * 16 + li) * 32 + g * 8);
#pragma unroll
    for (int n = 0; n < 4; ++n) bfm[n] = ld8(Bs + (wn + n * 16 + li) * 32 + g * 8);
#pragma unroll
    for (int m = 0; m < 4; ++m)
#pragma unroll
      for (int n = 0; n < 4; ++n)
        acc[m][n] = mfma16(af[m], bfm[n], acc[m][n]);
  }
#pragma unroll
  for (int m = 0; m < 4; ++m)
#pragma unroll
    for (int n = 0; n < 4; ++n) {
      int row = tm + wm + m * 16 + g * 4;
      int col = tn + wn + n * 16 + li;
#pragma unroll
      for (int r = 0; r < 4; ++r) {
        float v = acc[m][n][r];
        if (OUT_BF16) ((u16*)Cv)[(size_t)(row + r) * Ncols + col] = f2bf(v);
        else          ((float*)Cv)[(size_t)(row + r) * Ncols + col] = v;
      }
    }
}

// ------------- RMS qk-norm: Cq bf16 [4096][3072] -> q,k bf16 [b,h,n,d] -----
__global__ __launch_bounds__(256) void k_rms_qk(const u16* __restrict__ Cq,
                                                const float* __restrict__ gq,
                                                const float* __restrict__ gk,
                                                u16* __restrict__ qo,
                                                u16* __restrict__ ko) {
  int gid  = blockIdx.x * 4 + (threadIdx.x >> 6);   // 0..131071
  int lane = threadIdx.x & 63;
  int hh  = gid & 31;           // 0-15: q heads, 16-31: k heads
  int row = gid >> 5;           // 0..4095
  int b = row >> 11, n = row & 2047;
  bool isq = hh < 16;
  int h = hh & 15;
  int col = (isq ? 0 : 1024) + h * 64 + lane;
  float v = bf2f(Cq[(size_t)row * E3_ + col]);
  float ss = v * v;
  for (int off = 32; off; off >>= 1) ss += __shfl_xor(ss, off);
  float nrm = sqrtf(ss);
  float scale = 8.0f / fmaxf(nrm, 1e-12f);   // sqrt(64)=8
  const float* gam = isq ? gq : gk;
  float outv = v * scale * gam[h * 64 + lane];
  u16* dst = isq ? qo : ko;
  dst[(((size_t)(b * H_ + h)) * N_ + n) * 64 + lane] = f2bf(outv);
}

// ------------- V relayout: Cq[.,2048+h*64+d] -> vT [b*h][d][n] -------------
__global__ __launch_bounds__(256) void k_vt(const u16* __restrict__ Cq,
                                            u16* __restrict__ vT) {
  __shared__ float tile[64][65];
  int bh = blockIdx.y;
  int b = bh >> 4, h = bh & 15;
  int n0 = blockIdx.x * 64;
  int tx = threadIdx.x, ty = threadIdx.y;
  for (int i = 0; i < 64; i += 4) {
    int n = n0 + ty + i;
    tile[ty + i][tx] = bf2f(Cq[((size_t)(b * N_ + n)) * E3_ + 2048 + h * 64 + tx]);
  }
  __syncthreads();
  u16* dst = vT + (size_t)bh * 64 * N_;
  for (int i = 0; i < 64; i += 4) {
    int d = ty + i;
    dst[(size_t)d * N_ + n0 + tx] = f2bf(tile[tx][d]);
  }
}

// ------------- flash attention (swapped-operand, register softmax) ---------
// Per (b,h), 64 q-rows per block, 16 q per wave. S^T = mfma(K,Q) puts q on
// the lane index: softmax reduce = 15 in-lane ops + 2 shfl; rescale/l are
// lane-scalar; P->PV redistribution is 24 register shfl_xor (no LDS).
__global__ __launch_bounds__(256, 2) void k_attn(const u16* __restrict__ Q,
                                                 const u16* __restrict__ K,
                                                 const u16* __restrict__ Vt,
                                                 const float* __restrict__ bias,
                                                 u16* __restrict__ Out) {
  __shared__ float bias_s[N_];          // 8 KB
  int bh = blockIdx.y;
  int b = bh >> 4, h = bh & 15;
  int qb = blockIdx.x * 64;
  int tid = threadIdx.x, wave = tid >> 6, lane = tid & 63;
  int g = lane >> 4, li = lane & 15;
  int lo2 = g & 1, hi2 = g >> 1;
  const u16* Qh = Q  + (size_t)bh * N_ * 64;
  const u16* Kh = K  + (size_t)bh * N_ * 64;
  const u16* Vh = Vt + (size_t)bh * 64 * N_;

  for (int j = tid; j < N_; j += 256) bias_s[j] = bias[b * N_ + j];
  __syncthreads();

  int qr = qb + wave * 16 + li;
  short8 aq0 = ld8(Qh + (size_t)qr * 64 + g * 8);        // B-frag: Q[q=li][d g*8..]
  short8 aq1 = ld8(Qh + (size_t)qr * 64 + 32 + g * 8);

  f32x4 oT[4];                                            // O^T[d=dc*16+g*4+r][q=li]
#pragma unroll
  for (int dc = 0; dc < 4; ++dc) oT[dc] = (f32x4){0.f, 0.f, 0.f, 0.f};
  float m = -3e38f, l = 0.f;

  for (int kt = 0; kt < N_ / 64; ++kt) {
    int kbase = kt * 64;
    // ---- hoist ALL K and V fragment loads (independent; V covers softmax) --
    short8 kf[4][2], vf[4][2];
#pragma unroll
    for (int c = 0; c < 4; ++c) {
      const u16* kp = Kh + (size_t)(kbase + c * 16 + li) * 64 + g * 8;
      kf[c][0] = ld8(kp);
      kf[c][1] = ld8(kp + 32);
    }
#pragma unroll
    for (int dc = 0; dc < 4; ++dc) {
      const u16* vp = Vh + (size_t)(dc * 16 + li) * N_ + kbase + g * 8;
      vf[dc][0] = ld8(vp);
      vf[dc][1] = ld8(vp + 32);
    }
    // ---- S^T[c] : rows k_local=g*4+r, col q=li --------------------------
    f32x4 st[4];
#pragma unroll
    for (int c = 0; c < 4; ++c) {
      f32x4 z = (f32x4){0.f, 0.f, 0.f, 0.f};
      z = mfma16(kf[c][0], aq0, z);
      st[c] = mfma16(kf[c][1], aq1, z);
    }
    // ---- bias + tile max (in-lane over 16 k, then 2 shfl over g) --------
    float pv[4][4];
    float tmax = -3e38f;
#pragma unroll
    for (int c = 0; c < 4; ++c) {
      float4 bb = *(const float4*)&bias_s[kbase + c * 16 + g * 4];
      pv[c][0] = st[c][0] + bb.x; tmax = fmaxf(tmax, pv[c][0]);
      pv[c][1] = st[c][1] + bb.y; tmax = fmaxf(tmax, pv[c][1]);
      pv[c][2] = st[c][2] + bb.z; tmax = fmaxf(tmax, pv[c][2]);
      pv[c][3] = st[c][3] + bb.w; tmax = fmaxf(tmax, pv[c][3]);
    }
    tmax = fmaxf(tmax, __shfl_xor(tmax, 16));
    tmax = fmaxf(tmax, __shfl_xor(tmax, 32));
    float mn = fmaxf(m, tmax);
    float sc = __expf(m - mn);
    m = mn;
    float rs = 0.f;
#pragma unroll
    for (int c = 0; c < 4; ++c)
#pragma unroll
      for (int r = 0; r < 4; ++r) {
        float p = __expf(pv[c][r] - mn);
        pv[c][r] = p;
        rs += p;
      }
    rs += __shfl_xor(rs, 16);
    rs += __shfl_xor(rs, 32);
    l = l * sc + rs;
#pragma unroll
    for (int dc = 0; dc < 4; ++dc) oT[dc] *= sc;          // lane-scalar rescale
    // ---- pack P to bf16 pairs: w[c][rp] = P[li][c*16+g*4+2rp, +2rp+1] ----
    u32 w[4][2];
#pragma unroll
    for (int c = 0; c < 4; ++c)
#pragma unroll
      for (int rp = 0; rp < 2; ++rp)
        w[c][rp] = (u32)f2bf(pv[c][2 * rp]) | ((u32)f2bf(pv[c][2 * rp + 1]) << 16);
    // ---- lane exchange: build B-frags W[kh][t] = P[li][kh*32+g*8+2t,+2t+1]
    u32 W[2][4];
#pragma unroll
    for (int kh = 0; kh < 2; ++kh)
#pragma unroll
      for (int rp = 0; rp < 2; ++rp) {
        u32 f[2], s2[2];
#pragma unroll
        for (int cc = 0; cc < 2; ++cc) {
          u32 x = w[kh * 2 + cc][rp];
          u32 y = __shfl_xor(x, 16);   // lane g^1
          u32 u = __shfl_xor(x, 32);   // lane g^2
          u32 v = __shfl_xor(y, 32);   // lane g^3
          f[cc]  = lo2 ? (hi2 ? y : v) : (hi2 ? u : x);   // from g_src=2*(g&1)
          s2[cc] = lo2 ? (hi2 ? x : u) : (hi2 ? v : y);   // from g_src=2*(g&1)+1
        }
        W[kh][rp]     = hi2 ? f[1]  : f[0];
        W[kh][rp + 2] = hi2 ? s2[1] : s2[0];
      }
    union { u32 u4[4]; short8 s8; } cv0, cv1;
#pragma unroll
    for (int t = 0; t < 4; ++t) { cv0.u4[t] = W[0][t]; cv1.u4[t] = W[1][t]; }
    // ---- PV: O^T += V^T @ P^T ------------------------------------------
#pragma unroll
    for (int dc = 0; dc < 4; ++dc) {
      oT[dc] = mfma16(vf[dc][0], cv0.s8, oT[dc]);
      oT[dc] = mfma16(vf[dc][1], cv1.s8, oT[dc]);
    }
  }
  float inv = 1.0f / l;
#pragma unroll
  for (int dc = 0; dc < 4; ++dc) {
    ushort4 ov;
    ov.x = f2bf(oT[dc][0] * inv);
    ov.y = f2bf(oT[dc][1] * inv);
    ov.z = f2bf(oT[dc][2] * inv);
    ov.w = f2bf(oT[dc][3] * inv);
    *(ushort4*)&Out[((size_t)(b * N_ + qr)) * DIM_ + h * 64 + dc * 16 + g * 4] = ov;
  }
}

// ---------------------------------------------------------------------------
extern "C" void kernel_launch(void* const* d_in, const int* in_sizes, int n_in,
                              void* d_out, int out_size, void* d_ws, size_t ws_size,
                              hipStream_t stream) {
  const float* x    = (const float*)d_in[0];
  const int*   mask = (const int*)d_in[1];
  const float* g_ln = (const float*)d_in[2];
  const float* g_q  = (const float*)d_in[3];
  const float* g_k  = (const float*)d_in[4];
  const float* Wq   = (const float*)d_in[5];
  const float* Wkv  = (const float*)d_in[6];
  const float* Wo   = (const float*)d_in[7];
  float* out = (float*)d_out;

  char* ws = (char*)d_ws;
  u16*   xn   = (u16*)(ws);                         // 8 MB
  u16*   Wt   = (u16*)(ws + 8388608);               // 6 MB  (Wq^T | Wkv^T) [3072][1024]
  u16*   Wot  = (u16*)(ws + 14680064);              // 2 MB  Wo^T [1024][1024]
  float* bias = (float*)(ws + 16777216);            // 16 KB
  u16*   Cq   = (u16*)(ws + 16793600);              // 24 MB [4096][3072]
  u16*   qb   = (u16*)(ws + 41959424);              // 8 MB [b,h,n,d]
  u16*   kb   = (u16*)(ws + 41959424 + 8388608);    // 8 MB
  u16*   vT   = (u16*)(ws + 41959424 + 2*8388608);  // 8 MB [b*h][d][n]
  u16*   ao   = (u16*)(ws + 41959424 + 3*8388608);  // 8 MB [4096][1024]

  k_layernorm<<<ROWS_, 256, 0, stream>>>(x, g_ln, xn);
  dim3 tcb(32, 8);
  k_tcast<<<dim3(32, 32), tcb, 0, stream>>>(Wq,  Wt,               1024);
  k_tcast<<<dim3(64, 32), tcb, 0, stream>>>(Wkv, Wt + 1024 * 1024, 2048);
  k_tcast<<<dim3(32, 32), tcb, 0, stream>>>(Wo,  Wot,              1024);
  k_mask<<<1, 1024, 0, stream>>>(mask, bias);
  k_gemm_bt<true><<<dim3(32, 24), 256, 0, stream>>>(xn, Wt, Cq, ROWS_, E3_, DIM_);
  k_rms_qk<<<32768, 256, 0, stream>>>(Cq, g_q, g_k, qb, kb);
  k_vt<<<dim3(32, 32), dim3(64, 4), 0, stream>>>(Cq, vT);
  k_attn<<<dim3(32, 32), 256, 0, stream>>>(qb, kb, vT, bias, ao);
  k_gemm_bt<false><<<dim3(32, 8), 256, 0, stream>>>(ao, Wot, out, ROWS_, DIM_, DIM_);
}